// Round 5
// baseline (454.651 us; speedup 1.0000x reference)
//
#include <hip/hip_runtime.h>
#include <hip/hip_bf16.h>
#include <stdint.h>

#define NROWS 65536   // B*S = 16*4096
#define DDIM  256
#define KCAND 4096
#define CAP   48      // per-row candidate list slots
#define MARGIN1 8e-4f // phase-1 collect margin (worst-case bf16 err 2*2.2e-4 + tie grid)
#define MARGIN2 8e-4f // phase-2 prune margin

#define LSTRIDE 132   // LDS row stride in dwords (528B: 16B-aligned, banks spread 4*(ln+lq))
#define ROWS_PB 128   // rows per phase-1 block

typedef __bf16 bf16x8 __attribute__((ext_vector_type(8)));
typedef float  f32x4  __attribute__((ext_vector_type(4)));
typedef unsigned int u32;
typedef unsigned long long u64;

__device__ __forceinline__ u32 f2bf_u(float f) {
    u32 u = __float_as_uint(f);
    u += 0x7fffu + ((u >> 16) & 1u);
    return u >> 16;
}
__device__ __forceinline__ u32 pack2(float lo, float hi) { return f2bf_u(lo) | (f2bf_u(hi) << 16); }
__device__ __forceinline__ u32 fkey(float f) {
    u32 u = __float_as_uint(f);
    return (u & 0x80000000u) ? ~u : (u | 0x80000000u);
}
__device__ __forceinline__ float funkey(u32 k) {
    u32 u = (k & 0x80000000u) ? (k ^ 0x80000000u) : ~k;
    return __uint_as_float(u);
}
__device__ __forceinline__ float vmax4(f32x4 v) {
    return fmaxf(fmaxf(v[0], v[1]), fmaxf(v[2], v[3]));
}

// np-semantics exact distance: r = fl(fl(A + b_k) - acc_k), sequential ascending-d FMA
__device__ __forceinline__ float exact_r(const float* __restrict__ xr, float A,
                                         const float* __restrict__ er) {
    float b = 0.f, acc = 0.f;
    #pragma unroll 8
    for (int d = 0; d < DDIM; ++d) {
        float e = er[d];
        b   = fmaf(e, e, b);
        acc = fmaf(2.0f * xr[d], e, acc);
    }
    return (A + b) - acc;
}

// ---------------------------------------------------------------- convert
// ebf strip-major for SGPR+imm addressing in phase1:
//   frag(s,kc,u): 1KB block at offset ((s*8+kc)*4+u)*1024; lane L's 16B at +L*16
//   holds cand = s*64 + u*16 + (L&15), k = kc*32 + (L>>4)*8  (8 bf16).
__launch_bounds__(256)
__global__ void convert_e(const float* __restrict__ e, u32* __restrict__ ebf) {
    int T = blockIdx.x * blockDim.x + threadIdx.x;   // 131072 = 64 s * 8 kc * 4 u * 64 L
    int L = T & 63, u = (T >> 6) & 3, kc = (T >> 8) & 7, s = T >> 11;
    int cand = s * 64 + u * 16 + (L & 15);
    int k0 = kc * 32 + (L >> 4) * 8;
    const float4* src = (const float4*)(e + (size_t)cand * DDIM + k0);
    float4 a = src[0], b = src[1];
    uint4 o;
    o.x = pack2(a.x, a.y); o.y = pack2(a.z, a.w);
    o.z = pack2(b.x, b.y); o.w = pack2(b.z, b.w);
    ((uint4*)ebf)[T] = o;
}

// ---------------------------------------------------------------- phase 1
// 256 thr = 4 waves, tile 128 rows x 4096 cands.
// R4->R5: registers were the limiter (VGPR at 128-cap + 18MB spill-store
// signature in WRITE_SIZE; singleton fa invited [ds_read->wait->MFMA]
// serialization at ~2000cy/step). Changes:
//  * wave strip = 32 cands (it 0..31, strip=it*4+w): acc[8][2] = 64 regs
//    (was 128) -> deep register relief, no spill.
//  * fa[4] batched loads (two 4-rowblock halves): 4 ds_reads hoisted ahead
//    of 8 MFMAs each, breaking per-a serialization.
//  * bb quad-ring (prefetch distance 2, slot = kc&3 -> all-static indexing)
//    covers ~250cy L2 latency with ~2 steps of lead.
// PRE-PASS (its 0..1 = cands 0..255) seeds rowBestK; thresholds near-final.
__launch_bounds__(256, 2)
__global__ void phase1(const float* __restrict__ x, const u32* __restrict__ ebf,
                       u32* __restrict__ cnt, uint2* __restrict__ list) {
    __shared__ u32 lxd[ROWS_PB * LSTRIDE];   // 128 rows x 132 dwords (pad-4 banks)
    __shared__ u32 rowBestK[ROWS_PB];        // fkey(row acc-max), monotone under atomicMax

    const int tid = threadIdx.x;
    const int rowBase = blockIdx.x * ROWS_PB;
    if (tid < ROWS_PB) rowBestK[tid] = 0x007FFFFFu;   // fkey(-inf)

    // stage x tile once: fp32 -> bf16, linear rows (stride 132 dwords)
    {
        const float4* x4 = (const float4*)(x + (size_t)rowBase * DDIM);
        #pragma unroll
        for (int j = 0; j < 32; ++j) {
            int idx = j * 256 + tid;          // 0..8191 float4 chunks
            int r = idx >> 6, c4 = idx & 63;
            float4 v = x4[idx];
            *(uint2*)&lxd[r * LSTRIDE + 2 * c4] = make_uint2(pack2(v.x, v.y), pack2(v.z, v.w));
        }
    }
    __syncthreads();

    const int L = tid & 63;
    const int w = __builtin_amdgcn_readfirstlane(tid >> 6);   // force SGPR
    const int lq = L >> 4, ln = L & 15;
    const int vL = L << 4;                                     // lane byte offset in frag

    // wave sees strips it*4+w (32 cands each): s = it*2 + (w>>1), uoff = (w&1)*2
    // address(it,kc,u) = ebf + s*32768 + kc*4096 + (uoff+u)*1024 + vL
    const char* ebc_w2 = (const char*)ebf + (w >> 1) * 32768 + (w & 1) * 2048;

    auto loadG = [&](int it_, int kc_, bf16x8* dst) {
        const char* kb = ebc_w2 + (size_t)it_ * 65536 + kc_ * 4096;
        #pragma unroll
        for (int u = 0; u < 2; ++u)
            dst[u] = *(const bf16x8*)(kb + u * 1024 + vL);
    };

    // fa: one VGPR address, all reads at compile-time ds offsets (max ~59.5KB)
    const char* pa = (const char*)lxd + ln * (LSTRIDE * 4) + lq * 16;

    bf16x8 bbr[4][2];                        // quad ring, slot = kc&3 (static)
    f32x4 acc[8][2];
    const f32x4 Z4 = {0.f, 0.f, 0.f, 0.f};

    // ---- PRE-PASS: its 0..1 (cands 0..255) maxes only, seeds rowBestK ----
    loadG(0, 0, bbr[0]);
    loadG(0, 1, bbr[1]);
    #pragma unroll 1
    for (int pit = 0; pit < 2; ++pit) {
        #pragma unroll
        for (int kc = 0; kc < 8; ++kc) {
            int g = pit * 8 + kc;
            if (g + 2 < 16) {
                int itp = pit + (kc >= 6 ? 1 : 0);
                loadG(itp, (kc + 2) & 7, bbr[(kc + 2) & 3]);
            }
            #pragma unroll
            for (int h = 0; h < 2; ++h) {
                bf16x8 fa[4];
                #pragma unroll
                for (int t = 0; t < 4; ++t)
                    fa[t] = *(const bf16x8*)(pa + (h * 4 + t) * (16 * LSTRIDE * 4) + kc * 64);
                #pragma unroll
                for (int t = 0; t < 4; ++t)
                    #pragma unroll
                    for (int u = 0; u < 2; ++u)
                        acc[h * 4 + t][u] = (kc == 0)
                            ? __builtin_amdgcn_mfma_f32_16x16x32_bf16(bbr[0][u], fa[t], Z4, 0, 0, 0)
                            : __builtin_amdgcn_mfma_f32_16x16x32_bf16(bbr[kc & 3][u], fa[t], acc[h * 4 + t][u], 0, 0, 0);
            }
        }
        #pragma unroll
        for (int a = 0; a < 8; ++a) {
            float lmax = fmaxf(vmax4(acc[a][0]), vmax4(acc[a][1]));
            float m = fmaxf(lmax, __shfl_xor(lmax, 16, 64));
            m = fmaxf(m, __shfl_xor(m, 32, 64));
            if (lq == 0) atomicMax(&rowBestK[a * 16 + ln], fkey(m));
        }
    }
    __syncthreads();   // seeds visible before any collection

    // ---- MAIN LOOP: it=0..31 with collection ----
    loadG(0, 0, bbr[0]);   // re-prime ring (L2-hot)
    loadG(0, 1, bbr[1]);
    #pragma unroll 1
    for (int it = 0; it < 32; ++it) {
        #pragma unroll
        for (int kc = 0; kc < 8; ++kc) {
            int g = it * 8 + kc;
            if (g + 2 < 256) {
                int itp = it + (kc >= 6 ? 1 : 0);
                loadG(itp, (kc + 2) & 7, bbr[(kc + 2) & 3]);
            }
            #pragma unroll
            for (int h = 0; h < 2; ++h) {
                bf16x8 fa[4];
                #pragma unroll
                for (int t = 0; t < 4; ++t)
                    fa[t] = *(const bf16x8*)(pa + (h * 4 + t) * (16 * LSTRIDE * 4) + kc * 64);
                #pragma unroll
                for (int t = 0; t < 4; ++t)
                    #pragma unroll
                    for (int u = 0; u < 2; ++u)
                        acc[h * 4 + t][u] = (kc == 0)
                            ? __builtin_amdgcn_mfma_f32_16x16x32_bf16(bbr[0][u], fa[t], Z4, 0, 0, 0)
                            : __builtin_amdgcn_mfma_f32_16x16x32_bf16(bbr[kc & 3][u], fa[t], acc[h * 4 + t][u], 0, 0, 0);
            }
        }

        // epilogue for this strip (cands strip*32 .. +32), row-in-lane layout
        int strip = it * 4 + w;
        u32 seen[8];
        #pragma unroll
        for (int a = 0; a < 8; ++a) seen[a] = rowBestK[a * 16 + ln];   // broadcast reads, stale OK

        #pragma unroll
        for (int a = 0; a < 8; ++a) {
            float lmax = fmaxf(vmax4(acc[a][0]), vmax4(acc[a][1]));
            float m = fmaxf(lmax, __shfl_xor(lmax, 16, 64));
            m = fmaxf(m, __shfl_xor(m, 32, 64));
            if (lq == 0) atomicMax(&rowBestK[a * 16 + ln], fkey(m));   // fire-and-forget
            float eff  = fmaxf(m, funkey(seen[a]));   // own strip folded in via register
            float thrA = eff - 0.5f * MARGIN1;        // acc-space threshold
            if (__ballot(lmax >= thrA)) {             // usually nothing fires
                int c = 0;
                #pragma unroll
                for (int u = 0; u < 2; ++u)
                    #pragma unroll
                    for (int r = 0; r < 4; ++r)
                        c += (acc[a][u][r] >= thrA) ? 1 : 0;
                int p = c, t;
                t = __shfl_up(p, 16, 64); if (lq >= 1) p += t;
                t = __shfl_up(p, 32, 64); if (lq >= 2) p += t;
                int grow = rowBase + a * 16 + ln;
                u32 base = 0;
                if (lq == 3 && p > 0) base = atomicAdd(&cnt[grow], (u32)p);  // 16 distinct rows
                base = __shfl(base, 48 + ln, 64);     // broadcast from lq==3 lane of this row
                u32 pos = base + (u32)(p - c);
                #pragma unroll
                for (int u = 0; u < 2; ++u)
                    #pragma unroll
                    for (int r = 0; r < 4; ++r) {
                        float av = acc[a][u][r];
                        if (av >= thrA) {
                            if (pos < CAP)
                                list[(size_t)grow * CAP + pos] =
                                    make_uint2(__float_as_uint(-2.f * av),
                                               (u32)(strip * 32 + u * 16 + lq * 4 + r));
                            ++pos;
                        }
                    }
            }
        }
    }
}

// ---------------------------------------------------------------- phase 2 (fused)
// One wave per row, 4 waves/block. Fast paths (no x-load, no exact_r):
//   n==1: sole collected candidate wins (collection invariant).
//   unique margin-survivor: popc(ballot(vv<=mv+M2))==1 -> that candidate IS
//   the exact argmin (margin absorbs bf16 err + |e|^2 spread <=1.5e-5 << M2).
// Else: prune -> exact fp32 rescue (np-bit-exact, arithmetic untouched)
// -> packed shuffle-min tie-break. Then gather + write. No global atomics.
__launch_bounds__(256)
__global__ void phase2(const float* __restrict__ x, const float* __restrict__ emb,
                       const u32* __restrict__ cnt, const uint2* __restrict__ list,
                       float* __restrict__ outq, float* __restrict__ outp) {
    __shared__ float xs[4][DDIM];
    const int wid = threadIdx.x >> 6;
    const int row = blockIdx.x * 4 + wid;
    const int L   = threadIdx.x & 63;

    u32 n = cnt[row];
    u32 kstar;

    if (n == 1) {
        kstar = list[(size_t)row * CAP].y;    // unique candidate: no rescue needed
    } else {
        bool scan_all = (n > CAP);
        bool resolved = false;
        float vv = INFINITY; u32 kk = 0;
        bool surv = false;
        if (!scan_all) {
            if (L < (int)n) { uint2 e = list[(size_t)row * CAP + L]; vv = __uint_as_float(e.x); kk = e.y; }
            float mv = vv;
            #pragma unroll
            for (int o = 32; o; o >>= 1) mv = fminf(mv, __shfl_xor(mv, o, 64));
            surv = (L < (int)n) && (vv <= mv + MARGIN2);
            u64 bal = __ballot(surv);
            if (__popcll(bal) == 1) {          // unique margin-survivor = exact winner
                kstar = __shfl(kk, (int)(__ffsll(bal) - 1), 64);
                resolved = true;
            }
        }
        if (!resolved) {
            float4 v = ((const float4*)(x + (size_t)row * DDIM))[L];
            *(float4*)&xs[wid][L * 4] = v;
            double s = (double)v.x * v.x + (double)v.y * v.y + (double)v.z * v.z + (double)v.w * v.w;
            #pragma unroll
            for (int o = 32; o; o >>= 1) s += __shfl_xor(s, o, 64);
            float A = (float)s;

            u64 key = 0xFFFFFFFFFFFFFFFFull;
            if (!scan_all) {
                if (surv) {
                    float r = exact_r(xs[wid], A, emb + (size_t)kk * DDIM);
                    key = ((u64)fkey(r) << 32) | (u64)kk;
                }
            } else {
                for (int c = 0; c < KCAND / 64; ++c) {
                    u32 k = (u32)(c * 64 + L);
                    float r = exact_r(xs[wid], A, emb + (size_t)k * DDIM);
                    u64 cand = ((u64)fkey(r) << 32) | (u64)k;
                    key = (cand < key) ? cand : key;
                }
            }
            #pragma unroll
            for (int o = 32; o; o >>= 1) {
                u64 other = __shfl_xor(key, o, 64);
                key = (other < key) ? other : key;
            }
            kstar = (u32)(key & 0xFFFFFFFFull);
        }
    }

    float4 q = ((const float4*)(emb + (size_t)kstar * DDIM))[L];
    ((float4*)(outq + (size_t)row * DDIM))[L] = q;
    if (L == 0) outp[row] = (float)kstar;
}

// ---------------------------------------------------------------- launch
extern "C" void kernel_launch(void* const* d_in, const int* in_sizes, int n_in,
                              void* d_out, int out_size, void* d_ws, size_t ws_size,
                              hipStream_t stream) {
    const float* x   = (const float*)d_in[0];   // [65536, 256] fp32
    const float* emb = (const float*)d_in[1];   // [4096, 256] fp32
    float* outq = (float*)d_out;                      // [65536,256]
    float* outp = outq + (size_t)NROWS * DDIM;        // [65536]

    char* ws = (char*)d_ws;
    u32*   ebf  = (u32*)ws;                           // 2 MB (strip-major bf16)
    u32*   cnt  = (u32*)(ws + (2u << 20));            // 256 KB
    uint2* list = (uint2*)(ws + (3u << 20));          // 24 MB (total 27 MB)

    hipMemsetAsync(cnt, 0, (size_t)NROWS * sizeof(u32), stream);
    convert_e<<<512, 256, 0, stream>>>(emb, ebf);
    phase1<<<NROWS / ROWS_PB, 256, 0, stream>>>(x, ebf, cnt, list);
    phase2<<<NROWS / 4, 256, 0, stream>>>(x, emb, cnt, list, outq, outp);
}